// Round 10
// baseline (190.876 us; speedup 1.0000x reference)
//
#include <hip/hip_runtime.h>
#include <hip/hip_bf16.h>
#include <math.h>

#define OWN_DIM 7
#define INTR_DIM 5
#define N_HEADS 3
#define HEAD_DIM 5
#define N_INTR 256
#define HID 256
#define BATCH 16384
#define ROW 1287  // OWN_DIM + N_INTR*INTR_DIM

#define C2L 2.8853900817779268f       // 2*log2(e)
#define INV_C2L 0.34657359027997264f  // ln2/2

typedef __attribute__((ext_vector_type(8))) short bf16x8;
typedef __attribute__((ext_vector_type(4))) float f32x4;

__device__ __forceinline__ float leaky(float x) {
    return x > 0.0f ? x : 0.2f * x;
}

__device__ __forceinline__ unsigned short f2bf(float f) {
    union { float f; unsigned u; } v; v.f = f;
    unsigned r = (v.u + 0x7FFFu + ((v.u >> 16) & 1u)) >> 16;
    return (unsigned short)r;
}

__device__ __forceinline__ unsigned pkbf(float a, float b) {
    __hip_bfloat162 h2 = __float22bfloat162_rn(make_float2(a, b));
    unsigned u;
    __builtin_memcpy(&u, &h2, 4);
    return u;
}

// Kernel 1: attention -> x (B x 32 bf16: [own(7), context(15), zeros(10)]).
// 128-thr / 2-row blocks: LDS 10.3 KB -> 15 blocks/CU (94% occ), 2-wave barrier.
// Algebra (R9-proven): sc' = log2e*[sum(va) + sum_d (-2 va_d)/(1+e^{2(q_d+k_d)})];
// C2L folded into it/qb2 (bare v_exp), uniform softmax shift, un-scales in rden.
// Blocks 0-127 additionally do the W1/W2 -> bf16 col-major prep.
__global__ __launch_bounds__(128, 8) void attn_kernel(
    const float* __restrict__ obs,
    const float* __restrict__ Wq, const float* __restrict__ bq,
    const float* __restrict__ Wk, const float* __restrict__ bk,
    const float* __restrict__ Wv, const float* __restrict__ bv,
    const float* __restrict__ v_att, const float* __restrict__ temperature,
    const float* __restrict__ W1, const float* __restrict__ W2,
    unsigned short* __restrict__ xb,
    unsigned short* __restrict__ W1t, unsigned short* __restrict__ W2t)
{
    __shared__ __align__(8) float srow[2 * ROW + 2];
    int tid = threadIdx.x;

    // cooperative coalesced stage: 2 rows = 1287 float2s (8B-aligned for all blocks)
    {
        const float2* src = (const float2*)(obs + (size_t)blockIdx.x * 2 * ROW);
        float2* dst = (float2*)srow;
        #pragma unroll
        for (int i = 0; i < 10; i++) dst[tid + 128 * i] = src[tid + 128 * i];
        if (tid < 7) dst[1280 + tid] = src[1280 + tid];
    }
    __syncthreads();

    int wave = tid >> 6;
    int lane = tid & 63;
    int b = blockIdx.x * 2 + wave;
    const float* row = srow + wave * ROW;

    float absT = fabsf(temperature[0]);

    float own[7];
    #pragma unroll
    for (int o = 0; o < 7; o++) own[o] = row[o];

    // qb2[hd] = C2L*(bq+bk+own.Wq); m2va = -C2L*absT*va (log2-scaled)
    float qb2[15], m2va[15];
    #pragma unroll
    for (int hd = 0; hd < 15; hd++) {
        float acc = bq[hd] + bk[hd];
        #pragma unroll
        for (int o = 0; o < 7; o++) acc = fmaf(own[o], Wq[hd * 7 + o], acc);
        qb2[hd] = acc * C2L;
        m2va[hd] = -C2L * absT * v_att[hd];
    }
    float Sva[3], mshift[3];
    #pragma unroll
    for (int h = 0; h < 3; h++) {
        float s = 0.0f, a = 0.0f;
        #pragma unroll
        for (int d = 0; d < 5; d++) { s += m2va[h * 5 + d]; a += fabsf(m2va[h * 5 + d]); }
        Sva[h] = -0.5f * s;
        mshift[h] = fmaxf(0.0f, 1.5f * a - 100.0f);  // uniform softmax shift
    }

    // interactions: pre-scaled by C2L, pad flag on unscaled magnitudes
    float it[4][5];
    float asum[4];
    #pragma unroll
    for (int j = 0; j < 4; j++) {
        const float* ip = row + OWN_DIM + INTR_DIM * (lane + 64 * j);
        float a = 0.0f;
        #pragma unroll
        for (int i = 0; i < 5; i++) {
            float v = ip[i];
            it[j][i] = v * C2L;
            a += fabsf(v);
        }
        asum[j] = a;
    }

    float sc[3][4];
    #pragma unroll
    for (int j = 0; j < 4; j++) {
        bool pad = asum[j] < 1e-6f;
        #pragma unroll
        for (int h = 0; h < 3; h++) {
            float s = Sva[h];
            #pragma unroll
            for (int d = 0; d < 5; d++) {
                float y = qb2[h * 5 + d];
                #pragma unroll
                for (int i = 0; i < 5; i++)
                    y = fmaf(it[j][i], Wk[(h * 5 + d) * 5 + i], y);
                float t = __builtin_amdgcn_exp2f(y) + 1.0f;
                s = fmaf(m2va[h * 5 + d], __builtin_amdgcn_rcpf(t), s);
            }
            sc[h][j] = pad ? -INFINITY : s;
        }
    }

    // softmax over 256 per head: uniform shift (no max butterfly), sum butterfly
    float alpha[3][4];
    float sa[3];
    #pragma unroll
    for (int h = 0; h < 3; h++) {
        float lsum = 0.0f;
        #pragma unroll
        for (int j = 0; j < 4; j++) {
            alpha[h][j] = __builtin_amdgcn_exp2f(sc[h][j] - mshift[h]);
            lsum += alpha[h][j];
        }
        #pragma unroll
        for (int off = 32; off >= 1; off >>= 1) lsum += __shfl_xor(lsum, off);
        float rden = lsum > 0.0f ? INV_C2L * __builtin_amdgcn_rcpf(lsum) : 0.0f;
        sa[h] = lsum > 0.0f ? 1.0f : 0.0f;
        #pragma unroll
        for (int j = 0; j < 4; j++) alpha[h][j] *= rden;
    }

    // ctx partials + shuffle-butterfly reduction (independent VALU ops)
    float ctx[15];
    #pragma unroll
    for (int i = 0; i < 15; i++) ctx[i] = 0.0f;
    #pragma unroll
    for (int h = 0; h < 3; h++)
        #pragma unroll
        for (int j = 0; j < 4; j++) {
            float a = alpha[h][j];
            #pragma unroll
            for (int i = 0; i < 5; i++)
                ctx[h * 5 + i] = fmaf(a, it[j][i], ctx[h * 5 + i]);
        }
    #pragma unroll
    for (int hi = 0; hi < 15; hi++) {
        float v = ctx[hi];
        #pragma unroll
        for (int off = 32; off >= 1; off >>= 1) v += __shfl_xor(v, off);
        ctx[hi] = v;
    }

    // x = [own(7), Wv.ctx + bv*sa (15)]
    float x[22];
    #pragma unroll
    for (int o = 0; o < 7; o++) x[o] = own[o];
    #pragma unroll
    for (int k = 0; k < 15; k++) {
        int h = k / 5;
        float acc = bv[k] * sa[h];
        #pragma unroll
        for (int i = 0; i < 5; i++)
            acc = fmaf(Wv[k * 5 + i], ctx[h * 5 + i], acc);
        x[7 + k] = acc;
    }

    // pack to bf16 via cvt_pk; lanes 0-3 store 16B each -> 64B row
    unsigned up[12];
    #pragma unroll
    for (int i = 0; i < 11; i++) up[i] = pkbf(x[2 * i], x[2 * i + 1]);
    up[11] = 0u;
    uint4 u0 = { up[0], up[1], up[2],  up[3] };
    uint4 u1 = { up[4], up[5], up[6],  up[7] };
    uint4 u2 = { up[8], up[9], up[10], up[11] };
    uint4 u3 = { 0u, 0u, 0u, 0u };
    uint4 lo = (lane & 1) ? u1 : u0;
    uint4 hi = (lane & 1) ? u3 : u2;
    uint4 sel = (lane & 2) ? hi : lo;
    if (lane < 4) {
        *((uint4*)(xb + (size_t)b * 32 + lane * 8)) = sel;
    }

    // merged prep (blocks 0-127): W1 -> W1t (256x32 col-major bf16, K zero-pad),
    // W2 -> W2t (256x256 col-major bf16). mlp launches after attn completes.
    if (blockIdx.x < 128) {
        int idx = blockIdx.x * 128 + tid;   // 0..16383
        int col = idx & 255;
        int kq = idx >> 8;                  // 0..63
        ushort4 o;
        o.x = f2bf(W2[(kq * 4 + 0) * 256 + col]);
        o.y = f2bf(W2[(kq * 4 + 1) * 256 + col]);
        o.z = f2bf(W2[(kq * 4 + 2) * 256 + col]);
        o.w = f2bf(W2[(kq * 4 + 3) * 256 + col]);
        *((ushort4*)(W2t + col * 256 + kq * 4)) = o;
        if (kq < 8) {
            ushort4 p;
            int k = kq * 4;
            p.x = (k + 0) < 22 ? f2bf(W1[(k + 0) * 256 + col]) : 0;
            p.y = (k + 1) < 22 ? f2bf(W1[(k + 1) * 256 + col]) : 0;
            p.z = (k + 2) < 22 ? f2bf(W1[(k + 2) * 256 + col]) : 0;
            p.w = (k + 3) < 22 ? f2bf(W1[(k + 3) * 256 + col]) : 0;
            *((ushort4*)(W1t + col * 32 + k)) = p;
        }
    }
}

// Kernel 2: fused MLP. x -> h1 (W1 mfma, LDS) -> h2 (W2 mfma) -> Wf dot -> out.
__global__ __launch_bounds__(256, 2) void mlp_fused_kernel(
    const unsigned short* __restrict__ xb,
    const unsigned short* __restrict__ W1t, const unsigned short* __restrict__ W2t,
    const float* __restrict__ b1, const float* __restrict__ b2,
    const float* __restrict__ Wf, const float* __restrict__ bfv,
    const float* __restrict__ log_std, float* __restrict__ out)
{
    __shared__ unsigned short h1t[16 * 264];   // 16 rows x 264 bf16 (pad 8)
    __shared__ float finbuf[2][4][16][2];      // parity, wave, row, act

    int tid = threadIdx.x;
    int w = tid >> 6;
    int lane = tid & 63;
    int lm = lane & 15;
    int q = lane >> 4;
    int mbase = blockIdx.x * 32;

    float b1v[4], b2v[4], wf0[4], wf1[4];
    bf16x8 fw1[4];
    bf16x8 fw2[4][8];
    #pragma unroll
    for (int s = 0; s < 4; s++) {
        int col = w * 64 + s * 16 + lm;
        b1v[s] = b1[col];
        b2v[s] = b2[col];
        wf0[s] = Wf[col * 2];
        wf1[s] = Wf[col * 2 + 1];
        fw1[s] = *((const bf16x8*)(W1t + col * 32 + q * 8));
        #pragma unroll
        for (int t = 0; t < 8; t++)
            fw2[s][t] = *((const bf16x8*)(W2t + col * 256 + t * 32 + q * 8));
    }

    #pragma unroll
    for (int mt = 0; mt < 2; mt++) {
        int m0 = mbase + mt * 16;
        bf16x8 ax = *((const bf16x8*)(xb + (size_t)(m0 + lm) * 32 + q * 8));

        #pragma unroll
        for (int s = 0; s < 4; s++) {
            f32x4 c = {0.0f, 0.0f, 0.0f, 0.0f};
            c = __builtin_amdgcn_mfma_f32_16x16x32_bf16(ax, fw1[s], c, 0, 0, 0);
            int col = w * 64 + s * 16 + lm;
            #pragma unroll
            for (int i = 0; i < 4; i++)
                h1t[(q * 4 + i) * 264 + col] = f2bf(leaky(c[i] + b1v[s]));
        }
        __syncthreads();

        bf16x8 a2[8];
        #pragma unroll
        for (int t = 0; t < 8; t++)
            a2[t] = *((const bf16x8*)(h1t + lm * 264 + t * 32 + q * 8));

        float p0[4] = {0, 0, 0, 0};
        float p1[4] = {0, 0, 0, 0};
        #pragma unroll
        for (int s = 0; s < 4; s++) {
            f32x4 acc = {0.0f, 0.0f, 0.0f, 0.0f};
            #pragma unroll
            for (int t = 0; t < 8; t++)
                acc = __builtin_amdgcn_mfma_f32_16x16x32_bf16(a2[t], fw2[s][t], acc, 0, 0, 0);
            #pragma unroll
            for (int i = 0; i < 4; i++) {
                float h2 = leaky(acc[i] + b2v[s]);
                p0[i] = fmaf(h2, wf0[s], p0[i]);
                p1[i] = fmaf(h2, wf1[s], p1[i]);
            }
        }

        #pragma unroll
        for (int off = 1; off < 16; off <<= 1) {
            #pragma unroll
            for (int i = 0; i < 4; i++) {
                p0[i] += __shfl_xor(p0[i], off);
                p1[i] += __shfl_xor(p1[i], off);
            }
        }
        if (lm == 0) {
            #pragma unroll
            for (int i = 0; i < 4; i++) {
                finbuf[mt][w][q * 4 + i][0] = p0[i];
                finbuf[mt][w][q * 4 + i][1] = p1[i];
            }
        }
        __syncthreads();
        if (tid < 32) {
            int r = tid >> 1;
            int a = tid & 1;
            float s4 = finbuf[mt][0][r][a] + finbuf[mt][1][r][a]
                     + finbuf[mt][2][r][a] + finbuf[mt][3][r][a];
            out[(size_t)(m0 + r) * 4 + a] = s4 + bfv[a];
            out[(size_t)(m0 + r) * 4 + 2 + a] = log_std[a];
        }
    }
}

extern "C" void kernel_launch(void* const* d_in, const int* in_sizes, int n_in,
                              void* d_out, int out_size, void* d_ws, size_t ws_size,
                              hipStream_t stream) {
    const float* obs  = (const float*)d_in[0];
    const float* Wq   = (const float*)d_in[1];
    const float* bq   = (const float*)d_in[2];
    const float* Wk   = (const float*)d_in[3];
    const float* bk   = (const float*)d_in[4];
    const float* Wv   = (const float*)d_in[5];
    const float* bv   = (const float*)d_in[6];
    const float* v_att = (const float*)d_in[7];
    const float* temperature = (const float*)d_in[8];
    const float* W1   = (const float*)d_in[9];
    const float* b1   = (const float*)d_in[10];
    const float* W2   = (const float*)d_in[11];
    const float* b2   = (const float*)d_in[12];
    const float* Wf   = (const float*)d_in[13];
    const float* bf   = (const float*)d_in[14];
    const float* log_std = (const float*)d_in[15];
    float* out = (float*)d_out;

    unsigned short* xb  = (unsigned short*)d_ws;                        // 1 MiB
    unsigned short* W1t = xb + (size_t)BATCH * 32;                      // 16 KiB
    unsigned short* W2t = W1t + 256 * 32;                               // 128 KiB

    attn_kernel<<<BATCH / 2, 128, 0, stream>>>(
        obs, Wq, bq, Wk, bk, Wv, bv, v_att, temperature, W1, W2,
        xb, W1t, W2t);
    mlp_fused_kernel<<<BATCH / 32, 256, 0, stream>>>(
        xb, W1t, W2t, b1, b2, Wf, bf, log_std, out);
}

// Round 11
// 178.903 us; speedup vs baseline: 1.0669x; 1.0669x over previous
//
#include <hip/hip_runtime.h>
#include <hip/hip_bf16.h>
#include <math.h>

#define OWN_DIM 7
#define INTR_DIM 5
#define N_HEADS 3
#define HEAD_DIM 5
#define N_INTR 256
#define HID 256
#define BATCH 16384
#define ROW 1287  // OWN_DIM + N_INTR*INTR_DIM

#define C2L 2.8853900817779268f    // 2*log2(e)
#define INV_C2L 0.34657359027997264f  // 1/(2*log2(e)) = ln2/2

typedef __attribute__((ext_vector_type(8))) short bf16x8;
typedef __attribute__((ext_vector_type(4))) float f32x4;

__device__ __forceinline__ float leaky(float x) {
    return x > 0.0f ? x : 0.2f * x;
}

__device__ __forceinline__ unsigned short f2bf(float f) {
    union { float f; unsigned u; } v; v.f = f;
    unsigned r = (v.u + 0x7FFFu + ((v.u >> 16) & 1u)) >> 16;
    return (unsigned short)r;
}

__device__ __forceinline__ unsigned pkbf(float a, float b) {
    __hip_bfloat162 h2 = __float22bfloat162_rn(make_float2(a, b));
    unsigned u;
    __builtin_memcpy(&u, &h2, 4);
    return u;
}

// Kernel 1: attention -> x (B x 32 bf16: [own(7), context(15), zeros(10)]).
// One wave per row; obs rows staged f32 into LDS (R7/R9 skeleton, proven).
// Algebra: sc' = log2e*[sum(va) + sum_d (-2 va_d)/(1 + e^{2(q_d+k_d)})];
// 2*log2e folded into it/qb2 so exp2 is bare v_exp; uniform softmax shift
// (analytic bound) replaces the shuffle-max; un-scales folded into rden.
// Blocks 0-63 additionally do the W1/W2 -> bf16 col-major prep.
__global__ __launch_bounds__(256, 4) void attn_kernel(
    const float* __restrict__ obs,
    const float* __restrict__ Wq, const float* __restrict__ bq,
    const float* __restrict__ Wk, const float* __restrict__ bk,
    const float* __restrict__ Wv, const float* __restrict__ bv,
    const float* __restrict__ v_att, const float* __restrict__ temperature,
    const float* __restrict__ W1, const float* __restrict__ W2,
    unsigned short* __restrict__ xb,
    unsigned short* __restrict__ W1t, unsigned short* __restrict__ W2t)
{
    __shared__ __align__(16) float srow[4 * ROW + 4];
    int tid = threadIdx.x;

    // cooperative coalesced stage: 4 rows = 1287 float4s
    {
        const float4* src = (const float4*)(obs + (size_t)blockIdx.x * 4 * ROW);
        float4* dst = (float4*)srow;
        #pragma unroll
        for (int i = 0; i < 5; i++) dst[tid + 256 * i] = src[tid + 256 * i];
        if (tid < 7) dst[1280 + tid] = src[1280 + tid];
    }
    __syncthreads();

    int wave = tid >> 6;
    int lane = tid & 63;
    int b = blockIdx.x * 4 + wave;
    const float* row = srow + wave * ROW;

    float absT = fabsf(temperature[0]);

    float own[7];
    #pragma unroll
    for (int o = 0; o < 7; o++) own[o] = row[o];

    // qb2[hd] = C2L*(bq+bk+own.Wq); m2va = -C2L*absT*va (log2-scaled)
    float qb2[15], m2va[15];
    #pragma unroll
    for (int hd = 0; hd < 15; hd++) {
        float acc = bq[hd] + bk[hd];
        #pragma unroll
        for (int o = 0; o < 7; o++) acc = fmaf(own[o], Wq[hd * 7 + o], acc);
        qb2[hd] = acc * C2L;
        m2va[hd] = -C2L * absT * v_att[hd];
    }
    float Sva[3], mshift[3];
    #pragma unroll
    for (int h = 0; h < 3; h++) {
        float s = 0.0f, a = 0.0f;
        #pragma unroll
        for (int d = 0; d < 5; d++) { s += m2va[h * 5 + d]; a += fabsf(m2va[h * 5 + d]); }
        Sva[h] = -0.5f * s;
        mshift[h] = fmaxf(0.0f, 1.5f * a - 100.0f);  // uniform softmax shift
    }

    // interactions: pre-scaled by C2L, pad flag on unscaled magnitudes
    float it[4][5];
    float asum[4];
    #pragma unroll
    for (int j = 0; j < 4; j++) {
        const float* ip = row + OWN_DIM + INTR_DIM * (lane + 64 * j);
        float a = 0.0f;
        #pragma unroll
        for (int i = 0; i < 5; i++) {
            float v = ip[i];
            it[j][i] = v * C2L;
            a += fabsf(v);
        }
        asum[j] = a;
    }

    float sc[3][4];
    #pragma unroll
    for (int j = 0; j < 4; j++) {
        bool pad = asum[j] < 1e-6f;
        #pragma unroll
        for (int h = 0; h < 3; h++) {
            float s = Sva[h];
            #pragma unroll
            for (int d = 0; d < 5; d++) {
                float y = qb2[h * 5 + d];
                #pragma unroll
                for (int i = 0; i < 5; i++)
                    y = fmaf(it[j][i], Wk[(h * 5 + d) * 5 + i], y);
                float t = __builtin_amdgcn_exp2f(y) + 1.0f;
                s = fmaf(m2va[h * 5 + d], __builtin_amdgcn_rcpf(t), s);
            }
            sc[h][j] = pad ? -INFINITY : s;
        }
    }

    // softmax over 256 per head: uniform shift (no max butterfly), sum butterfly
    float alpha[3][4];
    float sa[3];
    #pragma unroll
    for (int h = 0; h < 3; h++) {
        float lsum = 0.0f;
        #pragma unroll
        for (int j = 0; j < 4; j++) {
            alpha[h][j] = __builtin_amdgcn_exp2f(sc[h][j] - mshift[h]);
            lsum += alpha[h][j];
        }
        #pragma unroll
        for (int off = 32; off >= 1; off >>= 1) lsum += __shfl_xor(lsum, off);
        float rden = lsum > 0.0f ? INV_C2L * __builtin_amdgcn_rcpf(lsum) : 0.0f;
        sa[h] = lsum > 0.0f ? 1.0f : 0.0f;
        #pragma unroll
        for (int j = 0; j < 4; j++) alpha[h][j] *= rden;
    }

    // ctx partials + shuffle-butterfly reduction (independent VALU ops)
    float ctx[15];
    #pragma unroll
    for (int i = 0; i < 15; i++) ctx[i] = 0.0f;
    #pragma unroll
    for (int h = 0; h < 3; h++)
        #pragma unroll
        for (int j = 0; j < 4; j++) {
            float a = alpha[h][j];
            #pragma unroll
            for (int i = 0; i < 5; i++)
                ctx[h * 5 + i] = fmaf(a, it[j][i], ctx[h * 5 + i]);
        }
    #pragma unroll
    for (int hi = 0; hi < 15; hi++) {
        float v = ctx[hi];
        #pragma unroll
        for (int off = 32; off >= 1; off >>= 1) v += __shfl_xor(v, off);
        ctx[hi] = v;
    }

    // x = [own(7), Wv.ctx + bv*sa (15)]
    float x[22];
    #pragma unroll
    for (int o = 0; o < 7; o++) x[o] = own[o];
    #pragma unroll
    for (int k = 0; k < 15; k++) {
        int h = k / 5;
        float acc = bv[k] * sa[h];
        #pragma unroll
        for (int i = 0; i < 5; i++)
            acc = fmaf(Wv[k * 5 + i], ctx[h * 5 + i], acc);
        x[7 + k] = acc;
    }

    // pack to bf16 via cvt_pk; lanes 0-3 store 16B each -> 64B row
    unsigned up[12];
    #pragma unroll
    for (int i = 0; i < 11; i++) up[i] = pkbf(x[2 * i], x[2 * i + 1]);
    up[11] = 0u;
    uint4 u0 = { up[0], up[1], up[2],  up[3] };
    uint4 u1 = { up[4], up[5], up[6],  up[7] };
    uint4 u2 = { up[8], up[9], up[10], up[11] };
    uint4 u3 = { 0u, 0u, 0u, 0u };
    uint4 lo = (lane & 1) ? u1 : u0;
    uint4 hi = (lane & 1) ? u3 : u2;
    uint4 sel = (lane & 2) ? hi : lo;
    if (lane < 4) {
        *((uint4*)(xb + (size_t)b * 32 + lane * 8)) = sel;
    }

    // merged prep (blocks 0-63): W1 -> W1t (256x32 col-major bf16, K zero-pad),
    // W2 -> W2t (256x256 col-major bf16). mlp launches after attn completes.
    if (blockIdx.x < 64) {
        int idx = blockIdx.x * 256 + tid;   // 0..16383
        int col = idx & 255;
        int kq = idx >> 8;                  // 0..63
        ushort4 o;
        o.x = f2bf(W2[(kq * 4 + 0) * 256 + col]);
        o.y = f2bf(W2[(kq * 4 + 1) * 256 + col]);
        o.z = f2bf(W2[(kq * 4 + 2) * 256 + col]);
        o.w = f2bf(W2[(kq * 4 + 3) * 256 + col]);
        *((ushort4*)(W2t + col * 256 + kq * 4)) = o;
        if (kq < 8) {
            ushort4 p;
            int k = kq * 4;
            p.x = (k + 0) < 22 ? f2bf(W1[(k + 0) * 256 + col]) : 0;
            p.y = (k + 1) < 22 ? f2bf(W1[(k + 1) * 256 + col]) : 0;
            p.z = (k + 2) < 22 ? f2bf(W1[(k + 2) * 256 + col]) : 0;
            p.w = (k + 3) < 22 ? f2bf(W1[(k + 3) * 256 + col]) : 0;
            *((ushort4*)(W1t + col * 32 + k)) = p;
        }
    }
}

// Kernel 2: fused MLP. x -> h1 (W1 mfma, LDS) -> h2 (W2 mfma) -> Wf dot -> out.
__global__ __launch_bounds__(256, 2) void mlp_fused_kernel(
    const unsigned short* __restrict__ xb,
    const unsigned short* __restrict__ W1t, const unsigned short* __restrict__ W2t,
    const float* __restrict__ b1, const float* __restrict__ b2,
    const float* __restrict__ Wf, const float* __restrict__ bfv,
    const float* __restrict__ log_std, float* __restrict__ out)
{
    __shared__ unsigned short h1t[16 * 264];   // 16 rows x 264 bf16 (pad 8)
    __shared__ float finbuf[2][4][16][2];      // parity, wave, row, act

    int tid = threadIdx.x;
    int w = tid >> 6;
    int lane = tid & 63;
    int lm = lane & 15;
    int q = lane >> 4;
    int mbase = blockIdx.x * 32;

    float b1v[4], b2v[4], wf0[4], wf1[4];
    bf16x8 fw1[4];
    bf16x8 fw2[4][8];
    #pragma unroll
    for (int s = 0; s < 4; s++) {
        int col = w * 64 + s * 16 + lm;
        b1v[s] = b1[col];
        b2v[s] = b2[col];
        wf0[s] = Wf[col * 2];
        wf1[s] = Wf[col * 2 + 1];
        fw1[s] = *((const bf16x8*)(W1t + col * 32 + q * 8));
        #pragma unroll
        for (int t = 0; t < 8; t++)
            fw2[s][t] = *((const bf16x8*)(W2t + col * 256 + t * 32 + q * 8));
    }

    #pragma unroll
    for (int mt = 0; mt < 2; mt++) {
        int m0 = mbase + mt * 16;
        bf16x8 ax = *((const bf16x8*)(xb + (size_t)(m0 + lm) * 32 + q * 8));

        #pragma unroll
        for (int s = 0; s < 4; s++) {
            f32x4 c = {0.0f, 0.0f, 0.0f, 0.0f};
            c = __builtin_amdgcn_mfma_f32_16x16x32_bf16(ax, fw1[s], c, 0, 0, 0);
            int col = w * 64 + s * 16 + lm;
            #pragma unroll
            for (int i = 0; i < 4; i++)
                h1t[(q * 4 + i) * 264 + col] = f2bf(leaky(c[i] + b1v[s]));
        }
        __syncthreads();

        bf16x8 a2[8];
        #pragma unroll
        for (int t = 0; t < 8; t++)
            a2[t] = *((const bf16x8*)(h1t + lm * 264 + t * 32 + q * 8));

        float p0[4] = {0, 0, 0, 0};
        float p1[4] = {0, 0, 0, 0};
        #pragma unroll
        for (int s = 0; s < 4; s++) {
            f32x4 acc = {0.0f, 0.0f, 0.0f, 0.0f};
            #pragma unroll
            for (int t = 0; t < 8; t++)
                acc = __builtin_amdgcn_mfma_f32_16x16x32_bf16(a2[t], fw2[s][t], acc, 0, 0, 0);
            #pragma unroll
            for (int i = 0; i < 4; i++) {
                float h2 = leaky(acc[i] + b2v[s]);
                p0[i] = fmaf(h2, wf0[s], p0[i]);
                p1[i] = fmaf(h2, wf1[s], p1[i]);
            }
        }

        #pragma unroll
        for (int off = 1; off < 16; off <<= 1) {
            #pragma unroll
            for (int i = 0; i < 4; i++) {
                p0[i] += __shfl_xor(p0[i], off);
                p1[i] += __shfl_xor(p1[i], off);
            }
        }
        if (lm == 0) {
            #pragma unroll
            for (int i = 0; i < 4; i++) {
                finbuf[mt][w][q * 4 + i][0] = p0[i];
                finbuf[mt][w][q * 4 + i][1] = p1[i];
            }
        }
        __syncthreads();
        if (tid < 32) {
            int r = tid >> 1;
            int a = tid & 1;
            float s4 = finbuf[mt][0][r][a] + finbuf[mt][1][r][a]
                     + finbuf[mt][2][r][a] + finbuf[mt][3][r][a];
            out[(size_t)(m0 + r) * 4 + a] = s4 + bfv[a];
            out[(size_t)(m0 + r) * 4 + 2 + a] = log_std[a];
        }
    }
}

extern "C" void kernel_launch(void* const* d_in, const int* in_sizes, int n_in,
                              void* d_out, int out_size, void* d_ws, size_t ws_size,
                              hipStream_t stream) {
    const float* obs  = (const float*)d_in[0];
    const float* Wq   = (const float*)d_in[1];
    const float* bq   = (const float*)d_in[2];
    const float* Wk   = (const float*)d_in[3];
    const float* bk   = (const float*)d_in[4];
    const float* Wv   = (const float*)d_in[5];
    const float* bv   = (const float*)d_in[6];
    const float* v_att = (const float*)d_in[7];
    const float* temperature = (const float*)d_in[8];
    const float* W1   = (const float*)d_in[9];
    const float* b1   = (const float*)d_in[10];
    const float* W2   = (const float*)d_in[11];
    const float* b2   = (const float*)d_in[12];
    const float* Wf   = (const float*)d_in[13];
    const float* bf   = (const float*)d_in[14];
    const float* log_std = (const float*)d_in[15];
    float* out = (float*)d_out;

    unsigned short* xb  = (unsigned short*)d_ws;                        // 1 MiB
    unsigned short* W1t = xb + (size_t)BATCH * 32;                      // 16 KiB
    unsigned short* W2t = W1t + 256 * 32;                               // 128 KiB

    attn_kernel<<<BATCH / 4, 256, 0, stream>>>(
        obs, Wq, bq, Wk, bk, Wv, bv, v_att, temperature, W1, W2,
        xb, W1t, W2t);
    mlp_fused_kernel<<<BATCH / 32, 256, 0, stream>>>(
        xb, W1t, W2t, b1, b2, Wf, bf, log_std, out);
}